// Round 1
// baseline (48873.196 us; speedup 1.0000x reference)
//
#include <hip/hip_runtime.h>
#include <math.h>

// Problem constants
#define NN     302      // state dim (N_ROOMS + 2)
#define MM     301      // input dim (N_ROOMS + 1)
#define NROOMS 300
#define NP     320      // padded dim: 320 = 8 waves * 40 cols = 5 * 64 rows
#define TT     60000
#define TS     59999    // number of steps
#define KN     2001     // tout knots
#define DTH    30.0f

// Workspace layout (in floats)
#define WS_M    0
#define WS_M2   102400
#define WS_M3   204800
#define WS_M4   307200
#define WS_P    409600
#define WS_UV   512000   // u1[320] u2[320] u3[320] u4[320] d[320]
#define WS_B0C  513600   // b0[320], c[320]
#define WS_TAU  514240   // float4 per step, 59999 entries

// ---------------------------------------------------------------------------
// K0: build M = h*A (320-padded, zero pad), b0 = B[:,0], c = B[:,1:]@Q
// A = W - diag(|W|.sum(axis=1)); W = theta_lo + (theta_hi-theta_lo)*sigmoid(params)
// One block of 320 threads.
__global__ void build_kernel(const float* __restrict__ params,
                             const float* __restrict__ tlo,
                             const float* __restrict__ thi,
                             const float* __restrict__ B,
                             float* __restrict__ M,
                             float* __restrict__ b0c)
{
    __shared__ float Qs[NROOMS];
    const int tid = threadIdx.x;
    if (tid < NROOMS) {
        const int idx = NN * NN + tid;
        const float x = 1.0f / (1.0f + expf(-params[idx]));
        Qs[tid] = tlo[idx] + (thi[idx] - tlo[idx]) * x;
    }
    __syncthreads();
    if (tid < NN) {
        const int r = tid;
        float rs = 0.0f, diagW = 0.0f;
        for (int c2 = 0; c2 < NN; ++c2) {
            const int idx = r * NN + c2;
            const float x  = 1.0f / (1.0f + expf(-params[idx]));
            const float wv = tlo[idx] + (thi[idx] - tlo[idx]) * x;
            rs += fabsf(wv);
            if (c2 == r) diagW = wv;
            M[r * NP + c2] = DTH * wv;
        }
        M[r * NP + r] = DTH * (diagW - rs);
        for (int c2 = NN; c2 < NP; ++c2) M[r * NP + c2] = 0.0f;
        const float b0v = B[r * MM];
        float cv = 0.0f;
        for (int q = 0; q < NROOMS; ++q) cv = fmaf(B[r * MM + 1 + q], Qs[q], cv);
        b0c[r] = b0v;
        b0c[NP + r] = cv;
    } else if (tid < NP) {
        for (int c2 = 0; c2 < NP; ++c2) M[tid * NP + c2] = 0.0f;
        b0c[tid] = 0.0f;
        b0c[NP + tid] = 0.0f;
    }
}

// ---------------------------------------------------------------------------
// K1: C = A*B, 320x320x320 fp32. grid (5, 320), block 64.
__global__ void matmul320(const float* __restrict__ A, const float* __restrict__ B,
                          float* __restrict__ C)
{
    const int c = blockIdx.x * 64 + threadIdx.x;
    const int r = blockIdx.y;
    float acc = 0.0f;
    for (int k = 0; k < NP; ++k) acc = fmaf(A[r * NP + k], B[k * NP + c], acc);
    C[r * NP + c] = acc;
}

// ---------------------------------------------------------------------------
// K2: P = I + M + M2/2 + M3/6 + M4/24. grid (5, 320), block 64.
__global__ void combineP(const float* __restrict__ M, const float* __restrict__ M2,
                         const float* __restrict__ M3, const float* __restrict__ M4,
                         float* __restrict__ P)
{
    const int c = blockIdx.x * 64 + threadIdx.x;
    const int r = blockIdx.y;
    const int i = r * NP + c;
    float v = M[i] + 0.5f * M2[i] + (1.0f / 6.0f) * M3[i] + (1.0f / 24.0f) * M4[i];
    if (r == c && r < NN) v += 1.0f;   // identity only on the real block
    P[i] = v;
}

// ---------------------------------------------------------------------------
// K3: forcing vectors. u1=(h/8)(I+M+M^2/3+M^3/3)b0, u2=(h/8)(3I+2M+M^2)b0,
// u3=(h/8)(3I+M)b0, u4=(h/8)b0, d=(h/8)(8I+4M+(4/3)M^2+(1/3)M^3)c.
// Also writes out[0:302] = iv. One block of 320 threads.
__global__ void vec_kernel(const float* __restrict__ M, const float* __restrict__ b0c,
                           float* __restrict__ uv, const float* __restrict__ iv,
                           float* __restrict__ out)
{
    __shared__ float v[NP];
    const int tid = threadIdx.x;  // 320
    const float s = DTH / 8.0f;
    const float* Mr = M + tid * NP;

    const float b0 = b0c[tid];
    v[tid] = b0; __syncthreads();
    float mb = 0.0f;  for (int j = 0; j < NP; ++j) mb  = fmaf(Mr[j], v[j], mb);
    __syncthreads(); v[tid] = mb;  __syncthreads();
    float m2b = 0.0f; for (int j = 0; j < NP; ++j) m2b = fmaf(Mr[j], v[j], m2b);
    __syncthreads(); v[tid] = m2b; __syncthreads();
    float m3b = 0.0f; for (int j = 0; j < NP; ++j) m3b = fmaf(Mr[j], v[j], m3b);

    uv[tid]          = s * (b0 + mb + (1.0f / 3.0f) * (m2b + m3b));
    uv[NP + tid]     = s * (3.0f * b0 + 2.0f * mb + m2b);
    uv[2 * NP + tid] = s * (3.0f * b0 + mb);
    uv[3 * NP + tid] = s * b0;

    const float cc = b0c[NP + tid];
    __syncthreads(); v[tid] = cc;  __syncthreads();
    float mc = 0.0f;  for (int j = 0; j < NP; ++j) mc  = fmaf(Mr[j], v[j], mc);
    __syncthreads(); v[tid] = mc;  __syncthreads();
    float m2c = 0.0f; for (int j = 0; j < NP; ++j) m2c = fmaf(Mr[j], v[j], m2c);
    __syncthreads(); v[tid] = m2c; __syncthreads();
    float m3c = 0.0f; for (int j = 0; j < NP; ++j) m3c = fmaf(Mr[j], v[j], m3c);

    uv[4 * NP + tid] = s * (8.0f * cc + 4.0f * mc + (4.0f / 3.0f) * m2c + (1.0f / 3.0f) * m3c);

    if (tid < NN) out[tid] = iv[tid];
}

// ---------------------------------------------------------------------------
// K4: per-step Tout interp coefficients at t, t+10, t+20, t+30 (np.interp clone)
__global__ void tau_kernel(const float* __restrict__ tout_t,
                           const float* __restrict__ tout_v,
                           const int* __restrict__ t0p,
                           float4* __restrict__ tau)
{
    const int n = blockIdx.x * 256 + threadIdx.x;
    if (n >= TS) return;
    const float tbase = 30.0f * (float)n + (float)(*t0p);
    float r[4];
    #pragma unroll
    for (int st = 0; st < 4; ++st) {
        const float x = tbase + 10.0f * (float)st;
        float res;
        if (x <= tout_t[0])            res = tout_v[0];
        else if (x >= tout_t[KN - 1])  res = tout_v[KN - 1];
        else {
            int k = (int)(x * (1.0f / 900.0f));
            if (k > KN - 2) k = KN - 2;
            if (k < 0) k = 0;
            if (x < tout_t[k] && k > 0) --k;
            else if (x >= tout_t[k + 1] && k < KN - 2) ++k;
            const float tk = tout_t[k], tk1 = tout_t[k + 1];
            const float wgt = (x - tk) / (tk1 - tk);
            res = tout_v[k] + wgt * (tout_v[k + 1] - tout_v[k]);
        }
        r[st] = res;
    }
    tau[n] = make_float4(r[0], r[1], r[2], r[3]);
}

// ---------------------------------------------------------------------------
// K5: sequential scan, single workgroup, P held in registers.
// y_{n+1} = P y_n + d + a.x*u1 + a.y*u2 + a.z*u3 + a.w*u4
// 512 threads = 8 waves; wave w owns cols [40w,40w+40); lane l owns rows {l+64k}.
__global__ __launch_bounds__(512) void scan_kernel(
    const float* __restrict__ P, const float* __restrict__ uv,
    const float4* __restrict__ tau, const float* __restrict__ iv,
    float* __restrict__ out)
{
    const int tid = threadIdx.x;
    const int w = tid >> 6;
    const int l = tid & 63;

    // Load P fragment: 5 rows x 40 cols = 200 VGPRs
    float p[5][40];
    #pragma unroll
    for (int k = 0; k < 5; ++k) {
        const float* Pr = P + (size_t)(l + 64 * k) * NP + 40 * w;
        #pragma unroll
        for (int j4 = 0; j4 < 10; ++j4) {
            const float4 v4 = *(const float4*)(Pr + 4 * j4);
            p[k][4 * j4 + 0] = v4.x; p[k][4 * j4 + 1] = v4.y;
            p[k][4 * j4 + 2] = v4.z; p[k][4 * j4 + 3] = v4.w;
        }
    }
    float du0 = 0.f, du1 = 0.f, du2 = 0.f, du3 = 0.f, dd = 0.f;
    if (tid < NP) {
        du0 = uv[tid]; du1 = uv[NP + tid]; du2 = uv[2 * NP + tid];
        du3 = uv[3 * NP + tid]; dd = uv[4 * NP + tid];
    }

    __shared__ float ybuf[NP];
    __shared__ float partial[8][NP];
    if (tid < NP) ybuf[tid] = (tid < NN) ? iv[tid] : 0.0f;
    __syncthreads();

    for (int n = 0; n < TS; ++n) {
        float acc0 = 0.f, acc1 = 0.f, acc2 = 0.f, acc3 = 0.f, acc4 = 0.f;
        const float* yb = ybuf + 40 * w;
        #pragma unroll
        for (int j4 = 0; j4 < 10; ++j4) {
            const float4 yv = *(const float4*)(yb + 4 * j4);
            const int j = 4 * j4;
            acc0 = fmaf(p[0][j + 0], yv.x, acc0); acc0 = fmaf(p[0][j + 1], yv.y, acc0);
            acc0 = fmaf(p[0][j + 2], yv.z, acc0); acc0 = fmaf(p[0][j + 3], yv.w, acc0);
            acc1 = fmaf(p[1][j + 0], yv.x, acc1); acc1 = fmaf(p[1][j + 1], yv.y, acc1);
            acc1 = fmaf(p[1][j + 2], yv.z, acc1); acc1 = fmaf(p[1][j + 3], yv.w, acc1);
            acc2 = fmaf(p[2][j + 0], yv.x, acc2); acc2 = fmaf(p[2][j + 1], yv.y, acc2);
            acc2 = fmaf(p[2][j + 2], yv.z, acc2); acc2 = fmaf(p[2][j + 3], yv.w, acc2);
            acc3 = fmaf(p[3][j + 0], yv.x, acc3); acc3 = fmaf(p[3][j + 1], yv.y, acc3);
            acc3 = fmaf(p[3][j + 2], yv.z, acc3); acc3 = fmaf(p[3][j + 3], yv.w, acc3);
            acc4 = fmaf(p[4][j + 0], yv.x, acc4); acc4 = fmaf(p[4][j + 1], yv.y, acc4);
            acc4 = fmaf(p[4][j + 2], yv.z, acc4); acc4 = fmaf(p[4][j + 3], yv.w, acc4);
        }
        partial[w][l]       = acc0;
        partial[w][l + 64]  = acc1;
        partial[w][l + 128] = acc2;
        partial[w][l + 192] = acc3;
        partial[w][l + 256] = acc4;
        __syncthreads();
        if (tid < NP) {
            float s = partial[0][tid] + partial[1][tid] + partial[2][tid] + partial[3][tid]
                    + partial[4][tid] + partial[5][tid] + partial[6][tid] + partial[7][tid];
            const float4 a = tau[n];
            float ynew = s + dd;
            ynew = fmaf(a.x, du0, ynew);
            ynew = fmaf(a.y, du1, ynew);
            ynew = fmaf(a.z, du2, ynew);
            ynew = fmaf(a.w, du3, ynew);
            ybuf[tid] = ynew;   // safe: all reads of ybuf finished before barrier above
            if (tid < NN) out[(size_t)(n + 1) * NN + tid] = ynew;
        }
        __syncthreads();
    }
}

// ---------------------------------------------------------------------------
extern "C" void kernel_launch(void* const* d_in, const int* in_sizes, int n_in,
                              void* d_out, int out_size, void* d_ws, size_t ws_size,
                              hipStream_t stream)
{
    const float* params = (const float*)d_in[0];
    const float* tlo    = (const float*)d_in[1];
    const float* thi    = (const float*)d_in[2];
    const float* B      = (const float*)d_in[3];
    const float* tout_t = (const float*)d_in[4];
    const float* tout_v = (const float*)d_in[5];
    const float* iv     = (const float*)d_in[6];
    // d_in[7] = t_eval: exact arithmetic progression (n*30 in fp32), not needed
    const int*   t0     = (const int*)d_in[8];
    float* out = (float*)d_out;
    float* ws  = (float*)d_ws;

    float*  M   = ws + WS_M;
    float*  M2  = ws + WS_M2;
    float*  M3  = ws + WS_M3;
    float*  M4  = ws + WS_M4;
    float*  P   = ws + WS_P;
    float*  UV  = ws + WS_UV;
    float*  B0C = ws + WS_B0C;
    float4* TAU = (float4*)(ws + WS_TAU);

    build_kernel<<<1, NP, 0, stream>>>(params, tlo, thi, B, M, B0C);
    matmul320<<<dim3(5, NP), 64, 0, stream>>>(M, M, M2);
    matmul320<<<dim3(5, NP), 64, 0, stream>>>(M2, M, M3);
    matmul320<<<dim3(5, NP), 64, 0, stream>>>(M2, M2, M4);
    combineP<<<dim3(5, NP), 64, 0, stream>>>(M, M2, M3, M4, P);
    vec_kernel<<<1, NP, 0, stream>>>(M, B0C, UV, iv, out);
    tau_kernel<<<(TS + 255) / 256, 256, 0, stream>>>(tout_t, tout_v, t0, TAU);
    scan_kernel<<<1, 512, 0, stream>>>(P, UV, TAU, iv, out);
}

// Round 2
// 1271.399 us; speedup vs baseline: 38.4405x; 38.4405x over previous
//
#include <hip/hip_runtime.h>
#include <math.h>

// Problem constants
#define NN     302      // state dim (N_ROOMS + 2)
#define MM     301      // input dim (N_ROOMS + 1)
#define NROOMS 300
#define NP     320      // padded dim: 320 = 8 waves * 40 cols = 5 * 64 rows
#define TS     59999    // number of steps
#define KN     2001     // tout knots
#define DTH    30.0f

// Time-chunking
#define L_CHUNK 256     // steps per chunk
#define N_CHUNK 235     // ceil(59999/256) chunks
#define N_BND   234     // boundary-chain steps (produce Y_1..Y_234)

// Workspace layout (in floats)
#define WS_M    0
#define WS_M2   102400
#define WS_M3   204800
#define WS_M4   307200
#define WS_P    409600
#define WS_UV   512000   // u1[320] u2[320] u3[320] u4[320] d[320]
#define WS_B0C  513600   // b0[320], c[320]
#define WS_TAU  514240   // float4 per step, 59999 entries -> 239996 floats
#define WS_W    754240   // 5 chains x 256 x 320 = 409600
#define WS_G    1163840  // 234 x 320
#define WS_Y    1238720  // 235 x 320
#define WS_PL   1313920  // P^256 fp32, 102400
#define WS_PD0  1416320  // fp64 (204800 floats)
#define WS_PD1  1621120  // fp64 (204800 floats)  -> total 1825920 floats = 7.3 MB

// ---------------------------------------------------------------------------
// K0: build M = h*A (320-padded, zero pad), b0 = B[:,0], c = B[:,1:]@Q
__global__ void build_kernel(const float* __restrict__ params,
                             const float* __restrict__ tlo,
                             const float* __restrict__ thi,
                             const float* __restrict__ B,
                             float* __restrict__ M,
                             float* __restrict__ b0c)
{
    __shared__ float Qs[NROOMS];
    const int tid = threadIdx.x;
    if (tid < NROOMS) {
        const int idx = NN * NN + tid;
        const float x = 1.0f / (1.0f + expf(-params[idx]));
        Qs[tid] = tlo[idx] + (thi[idx] - tlo[idx]) * x;
    }
    __syncthreads();
    if (tid < NN) {
        const int r = tid;
        float rs = 0.0f, diagW = 0.0f;
        for (int c2 = 0; c2 < NN; ++c2) {
            const int idx = r * NN + c2;
            const float x  = 1.0f / (1.0f + expf(-params[idx]));
            const float wv = tlo[idx] + (thi[idx] - tlo[idx]) * x;
            rs += fabsf(wv);
            if (c2 == r) diagW = wv;
            M[r * NP + c2] = DTH * wv;
        }
        M[r * NP + r] = DTH * (diagW - rs);
        for (int c2 = NN; c2 < NP; ++c2) M[r * NP + c2] = 0.0f;
        const float b0v = B[r * MM];
        float cv = 0.0f;
        for (int q = 0; q < NROOMS; ++q) cv = fmaf(B[r * MM + 1 + q], Qs[q], cv);
        b0c[r] = b0v;
        b0c[NP + r] = cv;
    } else if (tid < NP) {
        for (int c2 = 0; c2 < NP; ++c2) M[tid * NP + c2] = 0.0f;
        b0c[tid] = 0.0f;
        b0c[NP + tid] = 0.0f;
    }
}

// ---------------------------------------------------------------------------
// fp32 matmul 320^3: grid (5, 320), block 64.
__global__ void matmul320(const float* __restrict__ A, const float* __restrict__ B,
                          float* __restrict__ C)
{
    const int c = blockIdx.x * 64 + threadIdx.x;
    const int r = blockIdx.y;
    float acc = 0.0f;
    for (int k = 0; k < NP; ++k) acc = fmaf(A[r * NP + k], B[k * NP + c], acc);
    C[r * NP + c] = acc;
}

// fp64 matmul 320^3 (for P^256 squarings)
__global__ void matmul320_f64(const double* __restrict__ A, const double* __restrict__ B,
                              double* __restrict__ C)
{
    const int c = blockIdx.x * 64 + threadIdx.x;
    const int r = blockIdx.y;
    double acc = 0.0;
    for (int k = 0; k < NP; ++k) acc = fma(A[r * NP + k], B[k * NP + c], acc);
    C[r * NP + c] = acc;
}

__global__ void cast_f2d(const float* __restrict__ s, double* __restrict__ d)
{
    const int i = blockIdx.x * 256 + threadIdx.x;
    if (i < NP * NP) d[i] = (double)s[i];
}
__global__ void cast_d2f(const double* __restrict__ s, float* __restrict__ d)
{
    const int i = blockIdx.x * 256 + threadIdx.x;
    if (i < NP * NP) d[i] = (float)s[i];
}

// ---------------------------------------------------------------------------
// P = I + M + M2/2 + M3/6 + M4/24
__global__ void combineP(const float* __restrict__ M, const float* __restrict__ M2,
                         const float* __restrict__ M3, const float* __restrict__ M4,
                         float* __restrict__ P)
{
    const int c = blockIdx.x * 64 + threadIdx.x;
    const int r = blockIdx.y;
    const int i = r * NP + c;
    float v = M[i] + 0.5f * M2[i] + (1.0f / 6.0f) * M3[i] + (1.0f / 24.0f) * M4[i];
    if (r == c && r < NN) v += 1.0f;
    P[i] = v;
}

// ---------------------------------------------------------------------------
// forcing vectors + out[0:302] = iv
__global__ void vec_kernel(const float* __restrict__ M, const float* __restrict__ b0c,
                           float* __restrict__ uv, const float* __restrict__ iv,
                           float* __restrict__ out)
{
    __shared__ float v[NP];
    const int tid = threadIdx.x;  // 320
    const float s = DTH / 8.0f;
    const float* Mr = M + tid * NP;

    const float b0 = b0c[tid];
    v[tid] = b0; __syncthreads();
    float mb = 0.0f;  for (int j = 0; j < NP; ++j) mb  = fmaf(Mr[j], v[j], mb);
    __syncthreads(); v[tid] = mb;  __syncthreads();
    float m2b = 0.0f; for (int j = 0; j < NP; ++j) m2b = fmaf(Mr[j], v[j], m2b);
    __syncthreads(); v[tid] = m2b; __syncthreads();
    float m3b = 0.0f; for (int j = 0; j < NP; ++j) m3b = fmaf(Mr[j], v[j], m3b);

    uv[tid]          = s * (b0 + mb + (1.0f / 3.0f) * (m2b + m3b));
    uv[NP + tid]     = s * (3.0f * b0 + 2.0f * mb + m2b);
    uv[2 * NP + tid] = s * (3.0f * b0 + mb);
    uv[3 * NP + tid] = s * b0;

    const float cc = b0c[NP + tid];
    __syncthreads(); v[tid] = cc;  __syncthreads();
    float mc = 0.0f;  for (int j = 0; j < NP; ++j) mc  = fmaf(Mr[j], v[j], mc);
    __syncthreads(); v[tid] = mc;  __syncthreads();
    float m2c = 0.0f; for (int j = 0; j < NP; ++j) m2c = fmaf(Mr[j], v[j], m2c);
    __syncthreads(); v[tid] = m2c; __syncthreads();
    float m3c = 0.0f; for (int j = 0; j < NP; ++j) m3c = fmaf(Mr[j], v[j], m3c);

    uv[4 * NP + tid] = s * (8.0f * cc + 4.0f * mc + (4.0f / 3.0f) * m2c + (1.0f / 3.0f) * m3c);

    if (tid < NN) out[tid] = iv[tid];
}

// ---------------------------------------------------------------------------
// per-step Tout interp coefficients (np.interp clone)
__global__ void tau_kernel(const float* __restrict__ tout_t,
                           const float* __restrict__ tout_v,
                           const int* __restrict__ t0p,
                           float4* __restrict__ tau)
{
    const int n = blockIdx.x * 256 + threadIdx.x;
    if (n >= TS) return;
    const float tbase = 30.0f * (float)n + (float)(*t0p);
    float r[4];
    #pragma unroll
    for (int st = 0; st < 4; ++st) {
        const float x = tbase + 10.0f * (float)st;
        float res;
        if (x <= tout_t[0])            res = tout_v[0];
        else if (x >= tout_t[KN - 1])  res = tout_v[KN - 1];
        else {
            int k = (int)(x * (1.0f / 900.0f));
            if (k > KN - 2) k = KN - 2;
            if (k < 0) k = 0;
            if (x < tout_t[k] && k > 0) --k;
            else if (x >= tout_t[k + 1] && k < KN - 2) ++k;
            const float tk = tout_t[k], tk1 = tout_t[k + 1];
            const float wgt = (x - tk) / (tk1 - tk);
            res = tout_v[k] + wgt * (tout_v[k + 1] - tout_v[k]);
        }
        r[st] = res;
    }
    tau[n] = make_float4(r[0], r[1], r[2], r[3]);
}

// ---------------------------------------------------------------------------
// Shared matvec engine: 512 threads = 8 waves; wave w owns cols [40w,40w+40);
// lane l owns rows {l+64k}, k<5.  P fragment = 200 VGPRs/thread.
__device__ __forceinline__ void load_pfrag(const float* __restrict__ Psrc,
                                           float p[5][40], int l, int w)
{
    #pragma unroll
    for (int k = 0; k < 5; ++k) {
        const float* Pr = Psrc + (size_t)(l + 64 * k) * NP + 40 * w;
        #pragma unroll
        for (int j4 = 0; j4 < 10; ++j4) {
            const float4 v4 = *(const float4*)(Pr + 4 * j4);
            p[k][4 * j4 + 0] = v4.x; p[k][4 * j4 + 1] = v4.y;
            p[k][4 * j4 + 2] = v4.z; p[k][4 * j4 + 3] = v4.w;
        }
    }
}

// One matvec: returns (P*y)[tid] for tid<NP (garbage otherwise).
// Contains one internal __syncthreads(); caller must __syncthreads() after
// consuming the result / updating ybuf.
__device__ __forceinline__ float step_matvec(const float p[5][40],
                                             const float* __restrict__ ybuf,
                                             float* __restrict__ partial,
                                             int tid, int w, int l)
{
    float acc0 = 0.f, acc1 = 0.f, acc2 = 0.f, acc3 = 0.f, acc4 = 0.f;
    const float* yb = ybuf + 40 * w;
    #pragma unroll
    for (int j4 = 0; j4 < 10; ++j4) {
        const float4 yv = *(const float4*)(yb + 4 * j4);
        const int j = 4 * j4;
        acc0 = fmaf(p[0][j + 0], yv.x, acc0); acc0 = fmaf(p[0][j + 1], yv.y, acc0);
        acc0 = fmaf(p[0][j + 2], yv.z, acc0); acc0 = fmaf(p[0][j + 3], yv.w, acc0);
        acc1 = fmaf(p[1][j + 0], yv.x, acc1); acc1 = fmaf(p[1][j + 1], yv.y, acc1);
        acc1 = fmaf(p[1][j + 2], yv.z, acc1); acc1 = fmaf(p[1][j + 3], yv.w, acc1);
        acc2 = fmaf(p[2][j + 0], yv.x, acc2); acc2 = fmaf(p[2][j + 1], yv.y, acc2);
        acc2 = fmaf(p[2][j + 2], yv.z, acc2); acc2 = fmaf(p[2][j + 3], yv.w, acc2);
        acc3 = fmaf(p[3][j + 0], yv.x, acc3); acc3 = fmaf(p[3][j + 1], yv.y, acc3);
        acc3 = fmaf(p[3][j + 2], yv.z, acc3); acc3 = fmaf(p[3][j + 3], yv.w, acc3);
        acc4 = fmaf(p[4][j + 0], yv.x, acc4); acc4 = fmaf(p[4][j + 1], yv.y, acc4);
        acc4 = fmaf(p[4][j + 2], yv.z, acc4); acc4 = fmaf(p[4][j + 3], yv.w, acc4);
    }
    float* pw = partial + w * NP;
    pw[l]       = acc0;
    pw[l + 64]  = acc1;
    pw[l + 128] = acc2;
    pw[l + 192] = acc3;
    pw[l + 256] = acc4;
    __syncthreads();
    float s = 0.f;
    if (tid < NP) {
        s = partial[0 * NP + tid] + partial[1 * NP + tid] + partial[2 * NP + tid]
          + partial[3 * NP + tid] + partial[4 * NP + tid] + partial[5 * NP + tid]
          + partial[6 * NP + tid] + partial[7 * NP + tid];
    }
    return s;
}

// ---------------------------------------------------------------------------
// Phase B: 5 chains W_v[m] = P^m v, v in {d, u1..u4}. grid 5 x 512 threads.
__global__ __launch_bounds__(512, 2) void chains_kernel(
    const float* __restrict__ P, const float* __restrict__ uv,
    float* __restrict__ W)
{
    const int tid = threadIdx.x;
    const int w = tid >> 6, l = tid & 63;
    float p[5][40];
    load_pfrag(P, p, l, w);

    __shared__ float ybuf[NP];
    __shared__ float partial[8 * NP];
    const int v = blockIdx.x;
    float* Wv = W + (size_t)v * L_CHUNK * NP;
    const float* base = (v == 0) ? (uv + 4 * NP) : (uv + (v - 1) * NP);
    if (tid < NP) { const float b = base[tid]; ybuf[tid] = b; Wv[tid] = b; }
    __syncthreads();

    for (int m = 1; m < L_CHUNK; ++m) {
        const float s = step_matvec(p, ybuf, partial, tid, w, l);
        if (tid < NP) { ybuf[tid] = s; Wv[(size_t)m * NP + tid] = s; }
        __syncthreads();
    }
}

// ---------------------------------------------------------------------------
// Phase C: G_c = sum_m (Wd[m] + tau.x*W1[m] + ...), grid (5, 234) x 64.
__global__ void gsum_kernel(const float* __restrict__ W,
                            const float4* __restrict__ tau,
                            float* __restrict__ G)
{
    const int r = blockIdx.x * 64 + threadIdx.x;
    const int c = blockIdx.y;
    const float* W0 = W;
    const float* W1 = W + 1 * (size_t)L_CHUNK * NP;
    const float* W2 = W + 2 * (size_t)L_CHUNK * NP;
    const float* W3 = W + 3 * (size_t)L_CHUNK * NP;
    const float* W4 = W + 4 * (size_t)L_CHUNK * NP;
    const int nbase = c * L_CHUNK + L_CHUNK - 1;
    float g = 0.f;
    for (int m = 0; m < L_CHUNK; ++m) {
        const float4 a = tau[nbase - m];
        const size_t o = (size_t)m * NP + r;
        float t = W0[o];
        t = fmaf(a.x, W1[o], t);
        t = fmaf(a.y, W2[o], t);
        t = fmaf(a.z, W3[o], t);
        t = fmaf(a.w, W4[o], t);
        g += t;
    }
    G[(size_t)c * NP + r] = g;
}

// ---------------------------------------------------------------------------
// Phase D: boundary chain Y_{c+1} = P^256 Y_c + G_c. 1 WG x 512.
__global__ __launch_bounds__(512, 2) void boundary_kernel(
    const float* __restrict__ PL, const float* __restrict__ G,
    const float* __restrict__ iv, float* __restrict__ Y)
{
    const int tid = threadIdx.x;
    const int w = tid >> 6, l = tid & 63;
    float p[5][40];
    load_pfrag(PL, p, l, w);

    __shared__ float ybuf[NP];
    __shared__ float partial[8 * NP];
    if (tid < NP) { const float y0 = (tid < NN) ? iv[tid] : 0.f; ybuf[tid] = y0; Y[tid] = y0; }
    __syncthreads();

    for (int c = 0; c < N_BND; ++c) {
        const float s = step_matvec(p, ybuf, partial, tid, w, l);
        if (tid < NP) {
            const float yn = s + G[(size_t)c * NP + tid];
            ybuf[tid] = yn;
            Y[(size_t)(c + 1) * NP + tid] = yn;
        }
        __syncthreads();
    }
}

// ---------------------------------------------------------------------------
// Phase E: refill. grid 235 WGs x 512; WG c runs steps n in [256c, min(256c+256,TS)).
__global__ __launch_bounds__(512, 2) void refill_kernel(
    const float* __restrict__ P, const float* __restrict__ uv,
    const float4* __restrict__ tau, const float* __restrict__ Y,
    float* __restrict__ out)
{
    const int tid = threadIdx.x;
    const int w = tid >> 6, l = tid & 63;
    float p[5][40];
    load_pfrag(P, p, l, w);

    float du0 = 0.f, du1 = 0.f, du2 = 0.f, du3 = 0.f, dd = 0.f;
    if (tid < NP) {
        du0 = uv[tid]; du1 = uv[NP + tid]; du2 = uv[2 * NP + tid];
        du3 = uv[3 * NP + tid]; dd = uv[4 * NP + tid];
    }

    __shared__ float ybuf[NP];
    __shared__ float partial[8 * NP];
    const int c = blockIdx.x;
    if (tid < NP) ybuf[tid] = Y[(size_t)c * NP + tid];
    __syncthreads();

    const int n0 = c * L_CHUNK;
    const int n1 = (n0 + L_CHUNK < TS) ? (n0 + L_CHUNK) : TS;
    for (int n = n0; n < n1; ++n) {
        const float s = step_matvec(p, ybuf, partial, tid, w, l);
        if (tid < NP) {
            const float4 a = tau[n];
            float yn = s + dd;
            yn = fmaf(a.x, du0, yn);
            yn = fmaf(a.y, du1, yn);
            yn = fmaf(a.z, du2, yn);
            yn = fmaf(a.w, du3, yn);
            ybuf[tid] = yn;
            if (tid < NN) out[(size_t)(n + 1) * NN + tid] = yn;
        }
        __syncthreads();
    }
}

// ---------------------------------------------------------------------------
extern "C" void kernel_launch(void* const* d_in, const int* in_sizes, int n_in,
                              void* d_out, int out_size, void* d_ws, size_t ws_size,
                              hipStream_t stream)
{
    const float* params = (const float*)d_in[0];
    const float* tlo    = (const float*)d_in[1];
    const float* thi    = (const float*)d_in[2];
    const float* B      = (const float*)d_in[3];
    const float* tout_t = (const float*)d_in[4];
    const float* tout_v = (const float*)d_in[5];
    const float* iv     = (const float*)d_in[6];
    const int*   t0     = (const int*)d_in[8];
    float* out = (float*)d_out;
    float* ws  = (float*)d_ws;

    float*  M   = ws + WS_M;
    float*  M2  = ws + WS_M2;
    float*  M3  = ws + WS_M3;
    float*  M4  = ws + WS_M4;
    float*  P   = ws + WS_P;
    float*  UV  = ws + WS_UV;
    float*  B0C = ws + WS_B0C;
    float4* TAU = (float4*)(ws + WS_TAU);
    float*  W   = ws + WS_W;
    float*  G   = ws + WS_G;
    float*  Y   = ws + WS_Y;
    float*  PL  = ws + WS_PL;
    double* PD0 = (double*)(ws + WS_PD0);
    double* PD1 = (double*)(ws + WS_PD1);

    // Phase A: model build
    build_kernel<<<1, NP, 0, stream>>>(params, tlo, thi, B, M, B0C);
    matmul320<<<dim3(5, NP), 64, 0, stream>>>(M, M, M2);
    matmul320<<<dim3(5, NP), 64, 0, stream>>>(M2, M, M3);
    matmul320<<<dim3(5, NP), 64, 0, stream>>>(M2, M2, M4);
    combineP<<<dim3(5, NP), 64, 0, stream>>>(M, M2, M3, M4, P);
    vec_kernel<<<1, NP, 0, stream>>>(M, B0C, UV, iv, out);
    tau_kernel<<<(TS + 255) / 256, 256, 0, stream>>>(tout_t, tout_v, t0, TAU);

    // P^256 via 8 fp64 squarings
    cast_f2d<<<(NP * NP + 255) / 256, 256, 0, stream>>>(P, PD0);
    double* a = PD0; double* b = PD1;
    for (int i = 0; i < 8; ++i) {
        matmul320_f64<<<dim3(5, NP), 64, 0, stream>>>(a, a, b);
        double* t = a; a = b; b = t;
    }
    cast_d2f<<<(NP * NP + 255) / 256, 256, 0, stream>>>(a, PL);

    // Phase B: forcing-basis chains (5 parallel CUs)
    chains_kernel<<<5, 512, 0, stream>>>(P, UV, W);

    // Phase C: per-chunk aggregated forcing
    gsum_kernel<<<dim3(5, N_BND), 64, 0, stream>>>(W, TAU, G);

    // Phase D: boundary chain (sequential over chunks)
    boundary_kernel<<<1, 512, 0, stream>>>(PL, G, iv, Y);

    // Phase E: parallel interior refill
    refill_kernel<<<N_CHUNK, 512, 0, stream>>>(P, UV, TAU, Y, out);
}

// Round 3
// 1128.912 us; speedup vs baseline: 43.2923x; 1.1262x over previous
//
#include <hip/hip_runtime.h>
#include <math.h>

// Problem constants
#define NN     302      // state dim (N_ROOMS + 2)
#define MM     301      // input dim (N_ROOMS + 1)
#define NROOMS 300
#define NP     320      // padded dim: 320 = 8 waves * 40 cols = 5 * 64 rows
#define TS     59999    // number of steps
#define KN     2001     // tout knots
#define DTH    30.0f

// Time-chunking
#define L_CHUNK 256     // steps per chunk
#define N_CHUNK 235     // ceil(59999/256) chunks
#define N_BND   234     // boundary-chain steps (produce Y_1..Y_234)

// Workspace layout (in floats)
#define WS_M    0        // 102400
#define WS_M2   102400   // 102400
#define WS_E    204800   // 102400  E = M/6 + M2/24
#define WS_P    307200   // 102400
#define WS_UV   409600   // 1600: u1,u2,u3,u4,d  (each NP)
#define WS_B0C  411200   // 640: b0[320], c[320]
#define WS_Q    411840   // 320
#define WS_TAU  412160   // 240000 (float4 x 59999)
#define WS_W    652160   // 5 x 256 x 320 = 409600 (fp32 forcing-basis chains)
#define WS_G    1061760  // 75200 (234 x 320, padded)
#define WS_Y    1137280  // 75200 (235 x 320)
#define WS_PL   1212480  // 102400 fp32 P^256
#define WS_PD0  1314880  // fp64 ping (204800 floats)
#define WS_PD1  1519680  // fp64 pong (204800 floats)
#define WS_PT0  1724480  // fp32 transpose ping (102400)
#define WS_PT1  1826880  // fp32 transpose pong (102400) -> total 1929280 fl = 7.7 MB

// ---------------------------------------------------------------------------
// Build W elementwise (coalesced): M = DTH * W, zero-padded to 320x320.
__global__ void sigw_kernel(const float* __restrict__ params,
                            const float* __restrict__ tlo,
                            const float* __restrict__ thi,
                            float* __restrict__ M)
{
    const int i = blockIdx.x * 256 + threadIdx.x;
    if (i >= NP * NP) return;
    const int r = i / NP, c = i - r * NP;
    float v = 0.0f;
    if (r < NN && c < NN) {
        const int idx = r * NN + c;
        const float x = 1.0f / (1.0f + expf(-params[idx]));
        v = DTH * (tlo[idx] + (thi[idx] - tlo[idx]) * x);
    }
    M[i] = v;
}

// Fix diagonal: M[r][r] -= sum_c |M[r][c]|  (wave-per-row reduction)
__global__ void rowfix_kernel(float* __restrict__ M)
{
    const int r = blockIdx.x;        // 0..319 (pad rows are all-zero; -=0 ok)
    const int l = threadIdx.x;       // 64
    float s = 0.0f;
    #pragma unroll
    for (int k = 0; k < 5; ++k) s += fabsf(M[r * NP + l + 64 * k]);
    #pragma unroll
    for (int off = 32; off > 0; off >>= 1) s += __shfl_xor(s, off, 64);
    if (l == 0) M[r * NP + r] -= s;
}

// Q vector
__global__ void q_kernel(const float* __restrict__ params,
                         const float* __restrict__ tlo,
                         const float* __restrict__ thi,
                         float* __restrict__ Q)
{
    const int q = threadIdx.x;
    if (q < NROOMS) {
        const int idx = NN * NN + q;
        const float x = 1.0f / (1.0f + expf(-params[idx]));
        Q[q] = tlo[idx] + (thi[idx] - tlo[idx]) * x;
    }
}

// b0 = B[:,0], c = B[:,1:] @ Q  (wave per row)
__global__ void b0c_kernel(const float* __restrict__ B, const float* __restrict__ Q,
                           float* __restrict__ b0c)
{
    const int r = blockIdx.x;        // 0..319
    const int l = threadIdx.x;       // 64
    if (r >= NN) {
        if (l == 0) { b0c[r] = 0.0f; b0c[NP + r] = 0.0f; }
        return;
    }
    float s = 0.0f;
    for (int q = l; q < NROOMS; q += 64) s = fmaf(B[r * MM + 1 + q], Q[q], s);
    #pragma unroll
    for (int off = 32; off > 0; off >>= 1) s += __shfl_xor(s, off, 64);
    if (l == 0) { b0c[r] = B[r * MM]; b0c[NP + r] = s; }
}

// ---------------------------------------------------------------------------
// fp32 matmul 320^3, 4 rows per thread: grid (5, 80), block 64.
__global__ void matmul4r(const float* __restrict__ A, const float* __restrict__ B,
                         float* __restrict__ C)
{
    const int c = blockIdx.x * 64 + threadIdx.x;
    const int r0 = blockIdx.y * 4;
    const float* Ar = A + (size_t)r0 * NP;
    float a0 = 0.f, a1 = 0.f, a2 = 0.f, a3 = 0.f;
    #pragma unroll 4
    for (int k = 0; k < NP; ++k) {
        const float b = B[(size_t)k * NP + c];
        a0 = fmaf(Ar[k], b, a0);
        a1 = fmaf(Ar[NP + k], b, a1);
        a2 = fmaf(Ar[2 * NP + k], b, a2);
        a3 = fmaf(Ar[3 * NP + k], b, a3);
    }
    C[(size_t)r0 * NP + c] = a0;
    C[(size_t)(r0 + 1) * NP + c] = a1;
    C[(size_t)(r0 + 2) * NP + c] = a2;
    C[(size_t)(r0 + 3) * NP + c] = a3;
}

// E = M/6 + M2/24 (elementwise)
__global__ void combineE(const float* __restrict__ M, const float* __restrict__ M2,
                         float* __restrict__ E)
{
    const int i = blockIdx.x * 256 + threadIdx.x;
    if (i >= NP * NP) return;
    E[i] = (1.0f / 6.0f) * M[i] + (1.0f / 24.0f) * M2[i];
}

// P = M2 @ E + (I + M + M2/2)  — matmul with epilogue, 4 rows/thread.
__global__ void matmulP(const float* __restrict__ M2, const float* __restrict__ E,
                        const float* __restrict__ M, float* __restrict__ P)
{
    const int c = blockIdx.x * 64 + threadIdx.x;
    const int r0 = blockIdx.y * 4;
    const float* Ar = M2 + (size_t)r0 * NP;
    float a0 = 0.f, a1 = 0.f, a2 = 0.f, a3 = 0.f;
    #pragma unroll 4
    for (int k = 0; k < NP; ++k) {
        const float b = E[(size_t)k * NP + c];
        a0 = fmaf(Ar[k], b, a0);
        a1 = fmaf(Ar[NP + k], b, a1);
        a2 = fmaf(Ar[2 * NP + k], b, a2);
        a3 = fmaf(Ar[3 * NP + k], b, a3);
    }
    float acc[4] = {a0, a1, a2, a3};
    #pragma unroll
    for (int u = 0; u < 4; ++u) {
        const int r = r0 + u;
        const size_t idx = (size_t)r * NP + c;
        float v = acc[u] + M[idx] + 0.5f * M2[idx];
        if (r == c && r < NN) v += 1.0f;
        P[idx] = v;
    }
}

// ---------------------------------------------------------------------------
// forcing vectors; also seeds W[v][0][:] and writes out[0:302] = iv
__global__ void vec_kernel(const float* __restrict__ M, const float* __restrict__ b0c,
                           float* __restrict__ uv, const float* __restrict__ iv,
                           float* __restrict__ W, float* __restrict__ out)
{
    __shared__ float v[NP];
    const int tid = threadIdx.x;  // 320
    const float s = DTH / 8.0f;
    const float* Mr = M + tid * NP;

    const float b0 = b0c[tid];
    v[tid] = b0; __syncthreads();
    float mb = 0.0f;  for (int j = 0; j < NP; ++j) mb  = fmaf(Mr[j], v[j], mb);
    __syncthreads(); v[tid] = mb;  __syncthreads();
    float m2b = 0.0f; for (int j = 0; j < NP; ++j) m2b = fmaf(Mr[j], v[j], m2b);
    __syncthreads(); v[tid] = m2b; __syncthreads();
    float m3b = 0.0f; for (int j = 0; j < NP; ++j) m3b = fmaf(Mr[j], v[j], m3b);

    const float u1 = s * (b0 + mb + (1.0f / 3.0f) * (m2b + m3b));
    const float u2 = s * (3.0f * b0 + 2.0f * mb + m2b);
    const float u3 = s * (3.0f * b0 + mb);
    const float u4 = s * b0;

    const float cc = b0c[NP + tid];
    __syncthreads(); v[tid] = cc;  __syncthreads();
    float mc = 0.0f;  for (int j = 0; j < NP; ++j) mc  = fmaf(Mr[j], v[j], mc);
    __syncthreads(); v[tid] = mc;  __syncthreads();
    float m2c = 0.0f; for (int j = 0; j < NP; ++j) m2c = fmaf(Mr[j], v[j], m2c);
    __syncthreads(); v[tid] = m2c; __syncthreads();
    float m3c = 0.0f; for (int j = 0; j < NP; ++j) m3c = fmaf(Mr[j], v[j], m3c);

    const float dd = s * (8.0f * cc + 4.0f * mc + (4.0f / 3.0f) * m2c + (1.0f / 3.0f) * m3c);

    uv[tid]          = u1;
    uv[NP + tid]     = u2;
    uv[2 * NP + tid] = u3;
    uv[3 * NP + tid] = u4;
    uv[4 * NP + tid] = dd;

    // seed doubling chains: W[v][m=0][:]  (v=0:d, v=1..4:u1..u4)
    W[(size_t)(0 << 8) * NP + tid] = dd;
    W[(size_t)(1 << 8) * NP + tid] = u1;
    W[(size_t)(2 << 8) * NP + tid] = u2;
    W[(size_t)(3 << 8) * NP + tid] = u3;
    W[(size_t)(4 << 8) * NP + tid] = u4;

    if (tid < NN) out[tid] = iv[tid];
}

// ---------------------------------------------------------------------------
// per-step Tout interp coefficients (np.interp clone)
__global__ void tau_kernel(const float* __restrict__ tout_t,
                           const float* __restrict__ tout_v,
                           const int* __restrict__ t0p,
                           float4* __restrict__ tau)
{
    const int n = blockIdx.x * 256 + threadIdx.x;
    if (n >= TS) return;
    const float tbase = 30.0f * (float)n + (float)(*t0p);
    float r[4];
    #pragma unroll
    for (int st = 0; st < 4; ++st) {
        const float x = tbase + 10.0f * (float)st;
        float res;
        if (x <= tout_t[0])            res = tout_v[0];
        else if (x >= tout_t[KN - 1])  res = tout_v[KN - 1];
        else {
            int k = (int)(x * (1.0f / 900.0f));
            if (k > KN - 2) k = KN - 2;
            if (k < 0) k = 0;
            if (x < tout_t[k] && k > 0) --k;
            else if (x >= tout_t[k + 1] && k < KN - 2) ++k;
            const float tk = tout_t[k], tk1 = tout_t[k + 1];
            const float wgt = (x - tk) / (tk1 - tk);
            res = tout_v[k] + wgt * (tout_v[k + 1] - tout_v[k]);
        }
        r[st] = res;
    }
    tau[n] = make_float4(r[0], r[1], r[2], r[3]);
}

// ---------------------------------------------------------------------------
// cast P fp32 -> PD0 fp64 and PT0f fp32 transpose
__global__ void castT_kernel(const float* __restrict__ P, double* __restrict__ PD,
                             float* __restrict__ PTf)
{
    const int i = blockIdx.x * 256 + threadIdx.x;
    if (i >= NP * NP) return;
    const int r = i / NP, c = i - r * NP;
    const float v = P[i];
    PD[i] = (double)v;
    PTf[(size_t)c * NP + r] = v;
}

// fp64 square + fp32 transposed copy of result: C = A@A, CTf = C^T.
// grid (5, 80), block 64, 4 rows/thread.
__global__ void sqT_kernel(const double* __restrict__ A, double* __restrict__ C,
                           float* __restrict__ CTf)
{
    const int c = blockIdx.x * 64 + threadIdx.x;
    const int r0 = blockIdx.y * 4;
    const double* Ar = A + (size_t)r0 * NP;
    double a0 = 0., a1 = 0., a2 = 0., a3 = 0.;
    #pragma unroll 4
    for (int k = 0; k < NP; ++k) {
        const double b = A[(size_t)k * NP + c];
        a0 = fma(Ar[k], b, a0);
        a1 = fma(Ar[NP + k], b, a1);
        a2 = fma(Ar[2 * NP + k], b, a2);
        a3 = fma(Ar[3 * NP + k], b, a3);
    }
    C[(size_t)r0 * NP + c] = a0;
    C[(size_t)(r0 + 1) * NP + c] = a1;
    C[(size_t)(r0 + 2) * NP + c] = a2;
    C[(size_t)(r0 + 3) * NP + c] = a3;
    float4 t = make_float4((float)a0, (float)a1, (float)a2, (float)a3);
    *(float4*)(CTf + (size_t)c * NP + r0) = t;   // r0 % 4 == 0, aligned
}

__global__ void cast_d2f(const double* __restrict__ s, float* __restrict__ d)
{
    const int i = blockIdx.x * 256 + threadIdx.x;
    if (i < NP * NP) d[i] = (float)s[i];
}

// ---------------------------------------------------------------------------
// Doubling level j: W[v][2^j + mo] = P^(2^j) @ W[v][mo] for all v, mo<2^j.
// PTf = transpose of P^(2^j) (fp32). 4 columns per block, 320 threads.
__global__ __launch_bounds__(320) void double_kernel(const float* __restrict__ PTf,
                                                     float* __restrict__ W, int j)
{
    const int tid = threadIdx.x;       // 320
    const int nc = 5 << j;
    const int c0 = blockIdx.x * 4;
    __shared__ float ys[4][NP];
    #pragma unroll
    for (int u = 0; u < 4; ++u) {
        const int ci = c0 + u;
        float val = 0.0f;
        if (ci < nc) {
            const int v = ci >> j, mo = ci & ((1 << j) - 1);
            val = W[(size_t)((v << 8) + mo) * NP + tid];
        }
        ys[u][tid] = val;
    }
    __syncthreads();
    float a0 = 0.f, a1 = 0.f, a2 = 0.f, a3 = 0.f;
    #pragma unroll 4
    for (int k = 0; k < NP; ++k) {
        const float p = PTf[(size_t)k * NP + tid];   // coalesced
        a0 = fmaf(p, ys[0][k], a0);
        a1 = fmaf(p, ys[1][k], a1);
        a2 = fmaf(p, ys[2][k], a2);
        a3 = fmaf(p, ys[3][k], a3);
    }
    const float acc[4] = {a0, a1, a2, a3};
    #pragma unroll
    for (int u = 0; u < 4; ++u) {
        const int ci = c0 + u;
        if (ci < nc) {
            const int v = ci >> j, mo = ci & ((1 << j) - 1);
            W[(size_t)((v << 8) + (1 << j) + mo) * NP + tid] = acc[u];
        }
    }
}

// ---------------------------------------------------------------------------
// G_c = sum_m (Wd[m] + tau.x*W1[m] + ...), grid (5, 234) x 64.
__global__ void gsum_kernel(const float* __restrict__ W,
                            const float4* __restrict__ tau,
                            float* __restrict__ G)
{
    const int r = blockIdx.x * 64 + threadIdx.x;
    const int c = blockIdx.y;
    const float* W0 = W;
    const float* W1 = W + 1 * (size_t)L_CHUNK * NP;
    const float* W2 = W + 2 * (size_t)L_CHUNK * NP;
    const float* W3 = W + 3 * (size_t)L_CHUNK * NP;
    const float* W4 = W + 4 * (size_t)L_CHUNK * NP;
    const int nbase = c * L_CHUNK + L_CHUNK - 1;
    float g = 0.f;
    for (int m = 0; m < L_CHUNK; ++m) {
        const float4 a = tau[nbase - m];
        const size_t o = (size_t)m * NP + r;
        float t = W0[o];
        t = fmaf(a.x, W1[o], t);
        t = fmaf(a.y, W2[o], t);
        t = fmaf(a.z, W3[o], t);
        t = fmaf(a.w, W4[o], t);
        g += t;
    }
    G[(size_t)c * NP + r] = g;
}

// ---------------------------------------------------------------------------
// Matvec engine (512 thr = 8 waves; wave w owns cols [40w,40w+40); lane l rows l+64k)
__device__ __forceinline__ void load_pfrag(const float* __restrict__ Psrc,
                                           float p[5][40], int l, int w)
{
    #pragma unroll
    for (int k = 0; k < 5; ++k) {
        const float* Pr = Psrc + (size_t)(l + 64 * k) * NP + 40 * w;
        #pragma unroll
        for (int j4 = 0; j4 < 10; ++j4) {
            const float4 v4 = *(const float4*)(Pr + 4 * j4);
            p[k][4 * j4 + 0] = v4.x; p[k][4 * j4 + 1] = v4.y;
            p[k][4 * j4 + 2] = v4.z; p[k][4 * j4 + 3] = v4.w;
        }
    }
}

__device__ __forceinline__ float step_matvec(const float p[5][40],
                                             const float* __restrict__ ybuf,
                                             float* __restrict__ partial,
                                             int tid, int w, int l)
{
    float acc0 = 0.f, acc1 = 0.f, acc2 = 0.f, acc3 = 0.f, acc4 = 0.f;
    const float* yb = ybuf + 40 * w;
    #pragma unroll
    for (int j4 = 0; j4 < 10; ++j4) {
        const float4 yv = *(const float4*)(yb + 4 * j4);
        const int j = 4 * j4;
        acc0 = fmaf(p[0][j + 0], yv.x, acc0); acc0 = fmaf(p[0][j + 1], yv.y, acc0);
        acc0 = fmaf(p[0][j + 2], yv.z, acc0); acc0 = fmaf(p[0][j + 3], yv.w, acc0);
        acc1 = fmaf(p[1][j + 0], yv.x, acc1); acc1 = fmaf(p[1][j + 1], yv.y, acc1);
        acc1 = fmaf(p[1][j + 2], yv.z, acc1); acc1 = fmaf(p[1][j + 3], yv.w, acc1);
        acc2 = fmaf(p[2][j + 0], yv.x, acc2); acc2 = fmaf(p[2][j + 1], yv.y, acc2);
        acc2 = fmaf(p[2][j + 2], yv.z, acc2); acc2 = fmaf(p[2][j + 3], yv.w, acc2);
        acc3 = fmaf(p[3][j + 0], yv.x, acc3); acc3 = fmaf(p[3][j + 1], yv.y, acc3);
        acc3 = fmaf(p[3][j + 2], yv.z, acc3); acc3 = fmaf(p[3][j + 3], yv.w, acc3);
        acc4 = fmaf(p[4][j + 0], yv.x, acc4); acc4 = fmaf(p[4][j + 1], yv.y, acc4);
        acc4 = fmaf(p[4][j + 2], yv.z, acc4); acc4 = fmaf(p[4][j + 3], yv.w, acc4);
    }
    float* pw = partial + w * NP;
    pw[l]       = acc0;
    pw[l + 64]  = acc1;
    pw[l + 128] = acc2;
    pw[l + 192] = acc3;
    pw[l + 256] = acc4;
    __syncthreads();
    float s = 0.f;
    if (tid < NP) {
        s = partial[0 * NP + tid] + partial[1 * NP + tid] + partial[2 * NP + tid]
          + partial[3 * NP + tid] + partial[4 * NP + tid] + partial[5 * NP + tid]
          + partial[6 * NP + tid] + partial[7 * NP + tid];
    }
    return s;
}

// ---------------------------------------------------------------------------
// Boundary chain: Y_{c+1} = P^256 Y_c + G_c. 1 WG x 512.
__global__ __launch_bounds__(512, 2) void boundary_kernel(
    const float* __restrict__ PL, const float* __restrict__ G,
    const float* __restrict__ iv, float* __restrict__ Y)
{
    const int tid = threadIdx.x;
    const int w = tid >> 6, l = tid & 63;
    float p[5][40];
    load_pfrag(PL, p, l, w);

    __shared__ float ybuf[NP];
    __shared__ float partial[8 * NP];
    if (tid < NP) { const float y0 = (tid < NN) ? iv[tid] : 0.f; ybuf[tid] = y0; Y[tid] = y0; }
    __syncthreads();

    for (int c = 0; c < N_BND; ++c) {
        const float s = step_matvec(p, ybuf, partial, tid, w, l);
        if (tid < NP) {
            const float yn = s + G[(size_t)c * NP + tid];
            ybuf[tid] = yn;
            Y[(size_t)(c + 1) * NP + tid] = yn;
        }
        __syncthreads();
    }
}

// ---------------------------------------------------------------------------
// Refill: grid 235 WGs x 512; WG c runs steps n in [256c, min(256c+256,TS)).
__global__ __launch_bounds__(512, 2) void refill_kernel(
    const float* __restrict__ P, const float* __restrict__ uv,
    const float4* __restrict__ tau, const float* __restrict__ Y,
    float* __restrict__ out)
{
    const int tid = threadIdx.x;
    const int w = tid >> 6, l = tid & 63;
    float p[5][40];
    load_pfrag(P, p, l, w);

    float du0 = 0.f, du1 = 0.f, du2 = 0.f, du3 = 0.f, dd = 0.f;
    if (tid < NP) {
        du0 = uv[tid]; du1 = uv[NP + tid]; du2 = uv[2 * NP + tid];
        du3 = uv[3 * NP + tid]; dd = uv[4 * NP + tid];
    }

    __shared__ float ybuf[NP];
    __shared__ float partial[8 * NP];
    const int c = blockIdx.x;
    if (tid < NP) ybuf[tid] = Y[(size_t)c * NP + tid];
    __syncthreads();

    const int n0 = c * L_CHUNK;
    const int n1 = (n0 + L_CHUNK < TS) ? (n0 + L_CHUNK) : TS;
    for (int n = n0; n < n1; ++n) {
        const float s = step_matvec(p, ybuf, partial, tid, w, l);
        if (tid < NP) {
            const float4 a = tau[n];
            float yn = s + dd;
            yn = fmaf(a.x, du0, yn);
            yn = fmaf(a.y, du1, yn);
            yn = fmaf(a.z, du2, yn);
            yn = fmaf(a.w, du3, yn);
            ybuf[tid] = yn;
            if (tid < NN) out[(size_t)(n + 1) * NN + tid] = yn;
        }
        __syncthreads();
    }
}

// ---------------------------------------------------------------------------
extern "C" void kernel_launch(void* const* d_in, const int* in_sizes, int n_in,
                              void* d_out, int out_size, void* d_ws, size_t ws_size,
                              hipStream_t stream)
{
    const float* params = (const float*)d_in[0];
    const float* tlo    = (const float*)d_in[1];
    const float* thi    = (const float*)d_in[2];
    const float* B      = (const float*)d_in[3];
    const float* tout_t = (const float*)d_in[4];
    const float* tout_v = (const float*)d_in[5];
    const float* iv     = (const float*)d_in[6];
    const int*   t0     = (const int*)d_in[8];
    float* out = (float*)d_out;
    float* ws  = (float*)d_ws;

    float*  M   = ws + WS_M;
    float*  M2  = ws + WS_M2;
    float*  E   = ws + WS_E;
    float*  P   = ws + WS_P;
    float*  UV  = ws + WS_UV;
    float*  B0C = ws + WS_B0C;
    float*  Q   = ws + WS_Q;
    float4* TAU = (float4*)(ws + WS_TAU);
    float*  W   = ws + WS_W;
    float*  G   = ws + WS_G;
    float*  Y   = ws + WS_Y;
    float*  PL  = ws + WS_PL;
    double* PD[2]  = { (double*)(ws + WS_PD0), (double*)(ws + WS_PD1) };
    float*  PTf[2] = { ws + WS_PT0, ws + WS_PT1 };

    const int NE = (NP * NP + 255) / 256;   // 400 blocks

    // Phase A: model build (parallel, coalesced)
    sigw_kernel<<<NE, 256, 0, stream>>>(params, tlo, thi, M);
    rowfix_kernel<<<NP, 64, 0, stream>>>(M);
    q_kernel<<<1, 320, 0, stream>>>(params, tlo, thi, Q);
    b0c_kernel<<<NP, 64, 0, stream>>>(B, Q, B0C);

    // Propagator P = I + M + M2/2 + M2@(M/6 + M2/24)
    matmul4r<<<dim3(5, 80), 64, 0, stream>>>(M, M, M2);
    combineE<<<NE, 256, 0, stream>>>(M, M2, E);
    matmulP<<<dim3(5, 80), 64, 0, stream>>>(M2, E, M, P);

    // Forcing vectors (+W level-0 seed, +out[0]=iv) and tau table
    vec_kernel<<<1, NP, 0, stream>>>(M, B0C, UV, iv, W, out);
    tau_kernel<<<(TS + 255) / 256, 256, 0, stream>>>(tout_t, tout_v, t0, TAU);

    // Squaring ladder (fp64) + W doubling (fp32), 8 levels
    castT_kernel<<<NE, 256, 0, stream>>>(P, PD[0], PTf[0]);
    for (int j = 0; j < 8; ++j) {
        const int nc = 5 << j;
        double_kernel<<<(nc + 3) / 4, NP, 0, stream>>>(PTf[j & 1], W, j);
        sqT_kernel<<<dim3(5, 80), 64, 0, stream>>>(PD[j & 1], PD[(j + 1) & 1], PTf[(j + 1) & 1]);
    }
    cast_d2f<<<NE, 256, 0, stream>>>(PD[0], PL);   // PD[0] holds P^256 after 8 swaps

    // Per-chunk aggregated forcing
    gsum_kernel<<<dim3(5, N_BND), 64, 0, stream>>>(W, TAU, G);

    // Boundary chain (sequential over chunks)
    boundary_kernel<<<1, 512, 0, stream>>>(PL, G, iv, Y);

    // Parallel interior refill
    refill_kernel<<<N_CHUNK, 512, 0, stream>>>(P, UV, TAU, Y, out);
}